// Round 4
// baseline (462.604 us; speedup 1.0000x reference)
//
#include <hip/hip_runtime.h>
#include <hip/hip_bf16.h>
#include <stdint.h>

// Problem: B=32, LH=2048, LT=2048, D=768
//   z1 = H @ W ; alpha = tanh(colmax(z1 @ T^T)) ; HT = alpha @ T
#define NB 32
#define LHD 2048
#define LTD 2048
#define DD 768

using bf16x8 = __attribute__((ext_vector_type(8))) __bf16;
using f32x4  = __attribute__((ext_vector_type(4))) float;
typedef unsigned short u16;

__device__ __forceinline__ u16 f2bf(float f) {
    union { float f; uint32_t u; } v; v.f = f;
    uint32_t u = v.u + 0x7FFFu + ((v.u >> 16) & 1u);
    return (u16)(u >> 16);
}

__device__ __forceinline__ void glds16(const u16* g, u16* l) {
    __builtin_amdgcn_global_load_lds(
        (const __attribute__((address_space(1))) unsigned int*)g,
        (__attribute__((address_space(3))) unsigned int*)l,
        16, 0, 0);
}

// ---------------- conversion kernels ----------------
__global__ void k_convert(const float* __restrict__ in, u16* __restrict__ out, int n4) {
    int i = blockIdx.x * 256 + threadIdx.x;
    int stride = gridDim.x * 256;
    for (; i < n4; i += stride) {
        float4 v = reinterpret_cast<const float4*>(in)[i];
        ushort4 o;
        o.x = f2bf(v.x); o.y = f2bf(v.y); o.z = f2bf(v.z); o.w = f2bf(v.w);
        reinterpret_cast<ushort4*>(out)[i] = o;
    }
}

__global__ void k_transpose_w(const float* __restrict__ W, u16* __restrict__ WT) {
    int idx = blockIdx.x * 256 + threadIdx.x;
    int k = idx / DD, n = idx % DD;
    WT[(size_t)n * DD + k] = f2bf(W[idx]);
}

// ---------------- 256x256-tile GEMM, reg-double-buffered 2-phase pipeline ----------------
// 8 waves (2Mx4N), per-wave 128x64 out; BK=32; 4-buffer LDS ring; stage t+3;
// counted vmcnt(8); XOR-swizzled LDS; ds_reads issued ONE PHASE ahead of use
// with counted lgkmcnt(4/8) so LDS latency hides under the MFMA cluster.
template<bool COLMAX, int M, int N, bool SHARED_B>
__global__ __launch_bounds__(512, 2)
void k_gemm256(const u16* __restrict__ Ab, const u16* __restrict__ Bb,
               u16* __restrict__ Cb, float* __restrict__ Pb)
{
    constexpr int K  = DD;       // 768
    constexpr int BK = 32;
    constexpr int NT = K / BK;   // 24 (even)
    constexpr int MT = M / 256, NTC = N / 256, TPB = MT * NTC;
    static_assert(NT % 2 == 0 && NT >= 8, "NT");

    // bijective XCD-aware swizzle (grids are multiples of 8)
    const int nwg = gridDim.x;
    const int w   = ((blockIdx.x & 7) * (nwg >> 3)) + (blockIdx.x >> 3);
    const int batch = w / TPB;
    const int rem   = w % TPB;
    const int mt = rem / NTC, nc = rem % NTC;

    const u16* A  = Ab + (size_t)batch * M * K + (size_t)mt * 256 * K;
    const u16* Bt = Bb + (SHARED_B ? (size_t)0 : (size_t)batch * N * K) + (size_t)nc * 256 * K;

    // A ring: [4][256][32] bf16 (64KB); B ring at +65536 B (64KB)
    __shared__ __align__(16) u16 smem[65536];

    const int tid  = threadIdx.x;
    const int wave = tid >> 6;
    const int lane = tid & 63;
    const int wr = wave >> 2, wc = wave & 3;   // 2x4 wave grid
    const int fr = lane & 15, kq = lane >> 4;

    // staging: pre-swizzled GLOBAL source, linear LDS dest
    const int c0  = wave * 128 + lane;
    const int c1  = c0 + 64;
    const int rp0 = c0 >> 2, rp1 = c1 >> 2;
    const int g0  = rp0 * K + ((((c0 & 3) ^ ((rp0 >> 1) & 3))) << 3);
    const int g1  = rp1 * K + ((((c1 & 3) ^ ((rp1 >> 1) & 3))) << 3);
    const int sA  = wave * 1024;

    // fragment read byte offsets (same XOR on read)
    const int xr  = (fr >> 1) & 3;
    const int afb = (wr * 128 + fr) * 64 + ((kq ^ xr) << 4);
    const int bfb = (wc * 64  + fr) * 64 + ((kq ^ xr) << 4);

    auto stageA = [&](int buf, int t) {
        const u16* Ag = A + t * BK;
        u16* s = smem + buf * 8192;
        glds16(Ag + g0, s + sA);
        glds16(Ag + g1, s + sA + 512);
    };
    auto stageB = [&](int buf, int t) {
        const u16* Bg = Bt + t * BK;
        u16* s = smem + 32768 + buf * 8192;
        glds16(Bg + g0, s + sA);
        glds16(Bg + g1, s + sA + 512);
    };

    f32x4 acc[8][4] = {};
    bf16x8 aP[4], aQ[4], bE[4], bO[4];

    // prologue: stage tiles 0..2; land tile 0; preload R_0_p0 (aP, bE)
    stageA(0, 0); stageB(0, 0);
    stageA(1, 1); stageB(1, 1);
    stageA(2, 2); stageB(2, 2);
    asm volatile("s_waitcnt vmcnt(8)" ::: "memory");
    __builtin_amdgcn_s_barrier();
    __builtin_amdgcn_sched_barrier(0);
    {
        const char* ca_ = (const char*)smem;
        #pragma unroll
        for (int m = 0; m < 4; ++m) aP[m] = *(const bf16x8*)(ca_ + afb + m * 1024);
        #pragma unroll
        for (int n = 0; n < 4; ++n) bE[n] = *(const bf16x8*)(ca_ + 65536 + bfb + n * 1024);
    }
    __builtin_amdgcn_sched_barrier(0);

// Per-tile body. BCUR/BNXT: parity-selected B frag sets. PF: stage T+3.
// VMN: mid-tile vmcnt literal. RD1: load next tile's (aP,BNXT). LG1: lgkm for P1.
#define TILE_BODY(T, BCUR, BNXT, PF, VMN, RD1, LG1)                            \
  {                                                                            \
    const char* ca_ = (const char*)smem + ((T) & 3) * 16384;                   \
    /* ---- P0: load aQ(=a1 of T); stage T+3; MFMA lower half ---- */          \
    _Pragma("unroll") for (int m = 0; m < 4; ++m)                              \
        aQ[m] = *(const bf16x8*)(ca_ + afb + (m + 4) * 1024);                  \
    if (PF) { stageA(((T) + 3) & 3, (T) + 3); stageB(((T) + 3) & 3, (T) + 3);} \
    __builtin_amdgcn_sched_barrier(0);                                         \
    asm volatile("s_waitcnt lgkmcnt(4)" ::: "memory");                         \
    __builtin_amdgcn_sched_barrier(0);                                         \
    __builtin_amdgcn_s_setprio(1);                                             \
    _Pragma("unroll") for (int m = 0; m < 4; ++m)                              \
      _Pragma("unroll") for (int n = 0; n < 4; ++n)                            \
        acc[m][n] = __builtin_amdgcn_mfma_f32_16x16x32_bf16(aP[m], BCUR[n], acc[m][n], 0, 0, 0); \
    __builtin_amdgcn_s_setprio(0);                                             \
    __builtin_amdgcn_sched_barrier(0);                                         \
    asm volatile("s_waitcnt vmcnt(" #VMN ")" ::: "memory");                    \
    __builtin_amdgcn_s_barrier();                                              \
    __builtin_amdgcn_sched_barrier(0);                                         \
    /* ---- P1: load next tile's (aP, BNXT); MFMA upper half ---- */           \
    if (RD1) {                                                                 \
      const char* na_ = (const char*)smem + (((T) + 1) & 3) * 16384;           \
      _Pragma("unroll") for (int m = 0; m < 4; ++m)                            \
          aP[m] = *(const bf16x8*)(na_ + afb + m * 1024);                      \
      _Pragma("unroll") for (int n = 0; n < 4; ++n)                            \
          BNXT[n] = *(const bf16x8*)(na_ + 65536 + bfb + n * 1024);            \
    }                                                                          \
    __builtin_amdgcn_sched_barrier(0);                                         \
    asm volatile("s_waitcnt lgkmcnt(" #LG1 ")" ::: "memory");                  \
    __builtin_amdgcn_sched_barrier(0);                                         \
    __builtin_amdgcn_s_setprio(1);                                             \
    _Pragma("unroll") for (int m = 0; m < 4; ++m)                              \
      _Pragma("unroll") for (int n = 0; n < 4; ++n)                            \
        acc[m + 4][n] = __builtin_amdgcn_mfma_f32_16x16x32_bf16(aQ[m], BCUR[n], acc[m + 4][n], 0, 0, 0); \
    __builtin_amdgcn_s_setprio(0);                                             \
    __builtin_amdgcn_sched_barrier(0);                                         \
    __builtin_amdgcn_s_barrier();                                              \
    __builtin_amdgcn_sched_barrier(0);                                         \
  }

    // main loop: tiles 0..NT-5 (all steady), in parity pairs
    #pragma unroll 1
    for (int t = 0; t < NT - 4; t += 2) {
        TILE_BODY(t,     bE, bO, 1, 8, 1, 8)
        TILE_BODY(t + 1, bO, bE, 1, 8, 1, 8)
    }
    // peeled tail: tiles NT-4 (even) .. NT-1 (odd)
    TILE_BODY(NT - 4, bE, bO, 1, 8, 1, 8)
    TILE_BODY(NT - 3, bO, bE, 0, 4, 1, 8)
    TILE_BODY(NT - 2, bE, bO, 0, 0, 1, 8)
    TILE_BODY(NT - 1, bO, bE, 0, 0, 0, 0)
#undef TILE_BODY

    if constexpr (!COLMAX) {
        // C/D layout: col = fr, row = kq*4 + r  [verified m89/m91]
        u16* C = Cb + (size_t)batch * M * N + (size_t)(mt * 256 + wr * 128) * N + nc * 256 + wc * 64;
        #pragma unroll
        for (int m = 0; m < 8; ++m)
            #pragma unroll
            for (int n = 0; n < 4; ++n)
                #pragma unroll
                for (int r = 0; r < 4; ++r)
                    C[(size_t)(m * 16 + kq * 4 + r) * N + n * 16 + fr] = f2bf(acc[m][n][r]);
    } else {
        __shared__ float cmax[2][256];
        #pragma unroll
        for (int n = 0; n < 4; ++n) {
            float v = -3.4e38f;
            #pragma unroll
            for (int m = 0; m < 8; ++m)
                #pragma unroll
                for (int r = 0; r < 4; ++r)
                    v = fmaxf(v, acc[m][n][r]);
            v = fmaxf(v, __shfl_xor(v, 16));
            v = fmaxf(v, __shfl_xor(v, 32));
            if (lane < 16) cmax[wr][wc * 64 + n * 16 + fr] = v;
        }
        __syncthreads();
        if (tid < 256) {
            float v = fmaxf(cmax[0][tid], cmax[1][tid]);
            Pb[((size_t)batch * MT + mt) * N + nc * 256 + tid] = v;
        }
    }
}

// alpha[b][t] = tanh(max over 8 row-tiles)
__global__ void k_alpha(const float* __restrict__ Pb, float* __restrict__ alpha) {
    int idx = blockIdx.x * 256 + threadIdx.x;   // NB*LTD
    int b = idx / LTD, tt = idx % LTD;
    float m = -3.4e38f;
    #pragma unroll
    for (int lt = 0; lt < 8; ++lt)
        m = fmaxf(m, Pb[((size_t)b * 8 + lt) * LTD + tt]);
    alpha[idx] = tanhf(m);
}

__global__ void k_ht_partial(const float* __restrict__ T, const float* __restrict__ alpha,
                             float* __restrict__ p2) {
    int bx = blockIdx.x;            // NB*3*8
    int tc = bx & 7;
    int r  = bx >> 3;
    int dc = r % 3, b = r / 3;
    int d = dc * 256 + threadIdx.x;
    const float* Tp = T + (size_t)b * LTD * DD + (size_t)tc * 256 * DD + d;
    const float* al = alpha + b * LTD + tc * 256;
    float s = 0.f;
    for (int t2 = 0; t2 < 256; ++t2)
        s += al[t2] * Tp[(size_t)t2 * DD];
    p2[((size_t)b * 8 + tc) * DD + d] = s;
}

__global__ void k_ht_reduce(const float* __restrict__ p2, float* __restrict__ out) {
    int idx = blockIdx.x * 256 + threadIdx.x;   // NB*DD
    int b = idx / DD, d = idx % DD;
    float s = 0.f;
    #pragma unroll
    for (int tc = 0; tc < 8; ++tc)
        s += p2[((size_t)b * 8 + tc) * DD + d];
    out[idx] = s;
}

extern "C" void kernel_launch(void* const* d_in, const int* in_sizes, int n_in,
                              void* d_out, int out_size, void* d_ws, size_t ws_size,
                              hipStream_t stream) {
    const float* H = (const float*)d_in[0];
    const float* T = (const float*)d_in[1];
    const float* W = (const float*)d_in[2];
    float* out = (float*)d_out;

    char* ws = (char*)d_ws;
    size_t off = 0;
    auto carve = [&](size_t bytes) -> void* {
        void* p = ws + off;
        off += (bytes + 255) & ~(size_t)255;
        return p;
    };
    u16*   R1    = (u16*)carve((size_t)NB * LHD * DD * 2);   // Hb, later reused as Tb
    u16*   z1    = (u16*)carve((size_t)NB * LHD * DD * 2);
    u16*   WT    = (u16*)carve((size_t)DD * DD * 2);
    float* Pb    = (float*)carve((size_t)NB * 8 * LTD * 4);
    float* alpha = (float*)carve((size_t)NB * LTD * 4);
    float* p2    = (float*)carve((size_t)NB * 8 * DD * 4);

    if (ws_size < off) return;

    const int n4 = NB * LHD * DD / 4;

    // 1. Hb = bf16(H)
    k_convert<<<4096, 256, 0, stream>>>(H, R1, n4);
    // 2. WT = bf16(W^T)
    k_transpose_w<<<(DD * DD) / 256, 256, 0, stream>>>(W, WT);
    // 3. z1 = Hb @ W   (grid 32*8*3 = 768)
    k_gemm256<false, LHD, DD, true>
        <<<NB * (LHD/256) * (DD/256), 512, 0, stream>>>(R1, WT, z1, nullptr);
    // 4. Tb = bf16(T) into R1 (Hb dead; stream-ordered)
    k_convert<<<4096, 256, 0, stream>>>(T, R1, n4);
    // 5. colmax(z1 @ T^T)  (grid 32*8*8 = 2048)
    k_gemm256<true, LHD, LTD, false>
        <<<NB * (LHD/256) * (LTD/256), 512, 0, stream>>>(z1, R1, nullptr, Pb);
    // 6. alpha = tanh(max)
    k_alpha<<<NB * LTD / 256, 256, 0, stream>>>(Pb, alpha);
    // 7-8. HT = alpha @ T (f32)
    k_ht_partial<<<NB * 3 * 8, 256, 0, stream>>>(T, alpha, p2);
    k_ht_reduce<<<NB * DD / 256, 256, 0, stream>>>(p2, out);
}

// Round 5
// 459.150 us; speedup vs baseline: 1.0075x; 1.0075x over previous
//
#include <hip/hip_runtime.h>
#include <hip/hip_bf16.h>
#include <stdint.h>

// Problem: B=32, LH=2048, LT=2048, D=768
//   z1 = H @ W ; alpha = tanh(colmax(z1 @ T^T)) ; HT = alpha @ T
#define NB 32
#define LHD 2048
#define LTD 2048
#define DD 768

using bf16x8 = __attribute__((ext_vector_type(8))) __bf16;
using f32x4  = __attribute__((ext_vector_type(4))) float;
typedef unsigned short u16;

__device__ __forceinline__ u16 f2bf(float f) {
    union { float f; uint32_t u; } v; v.f = f;
    uint32_t u = v.u + 0x7FFFu + ((v.u >> 16) & 1u);
    return (u16)(u >> 16);
}

__device__ __forceinline__ void glds16(const u16* g, u16* l) {
    __builtin_amdgcn_global_load_lds(
        (const __attribute__((address_space(1))) unsigned int*)g,
        (__attribute__((address_space(3))) unsigned int*)l,
        16, 0, 0);
}

// ---------------- conversion kernels ----------------
__global__ void k_convert(const float* __restrict__ in, u16* __restrict__ out, int n4) {
    int i = blockIdx.x * 256 + threadIdx.x;
    int stride = gridDim.x * 256;
    for (; i < n4; i += stride) {
        float4 v = reinterpret_cast<const float4*>(in)[i];
        ushort4 o;
        o.x = f2bf(v.x); o.y = f2bf(v.y); o.z = f2bf(v.z); o.w = f2bf(v.w);
        reinterpret_cast<ushort4*>(out)[i] = o;
    }
}

__global__ void k_transpose_w(const float* __restrict__ W, u16* __restrict__ WT) {
    int idx = blockIdx.x * 256 + threadIdx.x;
    int k = idx / DD, n = idx % DD;
    WT[(size_t)n * DD + k] = f2bf(W[idx]);
}

// ---------------- 256x128-tile GEMM, 2 blocks/CU for inter-block overlap ----------------
// A [M,K] row-major bf16; Bt [N,K] row-major bf16; K=768.
// 8 waves (4Mx2N), per-wave 64x64 out (acc 64 VGPR); BK=32; ring-3 LDS (74KB
// -> 2 blocks/CU, 4 waves/SIMD); stage t+2; vmcnt(3) counted wait; 1 barrier
// per K-tile; XOR-swizzled LDS (pre-swizzled global source, linear dest).
template<bool COLMAX, int M, int N, bool SHARED_B>
__global__ __launch_bounds__(512, 4)
void k_gemm(const u16* __restrict__ Ab, const u16* __restrict__ Bb,
            u16* __restrict__ Cb, float* __restrict__ Pb)
{
    constexpr int K  = DD;       // 768
    constexpr int BM = 256, BN = 128, BK = 32;
    constexpr int NT = K / BK;   // 24 (multiple of 3)
    constexpr int MT = M / BM, NTC = N / BN, TPB = MT * NTC;
    static_assert(NT % 3 == 0 && NT >= 9, "NT");

    // bijective XCD-aware swizzle (grids are multiples of 8)
    const int nwg = gridDim.x;
    const int w   = ((blockIdx.x & 7) * (nwg >> 3)) + (blockIdx.x >> 3);
    const int batch = w / TPB;
    const int rem   = w % TPB;
    const int mt = rem / NTC, nc = rem % NTC;

    const u16* A  = Ab + (size_t)batch * M * K + (size_t)mt * BM * K;
    const u16* Bt = Bb + (SHARED_B ? (size_t)0 : (size_t)batch * N * K) + (size_t)nc * BN * K;

    // ring-3: per buf 12288 elems = A[256][32] (8192) + B[128][32] (4096)
    __shared__ __align__(16) u16 smem[3 * 12288];          // 73728 B
    __shared__ float cmax[4][128];                          // +2 KB

    const int tid  = threadIdx.x;
    const int wave = tid >> 6;
    const int lane = tid & 63;
    const int wr = wave >> 1, wc = wave & 1;   // 4M x 2N wave grid
    const int fr = lane & 15, kq = lane >> 4;

    // staging: pre-swizzled GLOBAL source, linear LDS dest.
    // chunk c -> phys row rp=c>>2, slot cp=c&3 holds logical k-chunk cp^((rp>>1)&3)
    const int cA0 = tid,       rA0 = cA0 >> 2;
    const int gA0 = rA0 * K + ((((cA0 & 3) ^ ((rA0 >> 1) & 3))) << 3);
    const int cA1 = 512 + tid, rA1 = cA1 >> 2;
    const int gA1 = rA1 * K + ((((cA1 & 3) ^ ((rA1 >> 1) & 3))) << 3);
    const int sW  = wave * 512;   // per-wave LDS elem base within a line

    // fragment read byte offsets (same XOR on read)
    const int xr  = (fr >> 1) & 3;
    const int afb = (wr * 64 + fr) * 64 + ((kq ^ xr) << 4);
    const int bfb = (wc * 64 + fr) * 64 + ((kq ^ xr) << 4);

    auto stage = [&](int buf, int t) {
        u16* s = smem + buf * 12288;
        const u16* Ag = A  + t * BK;
        const u16* Bg = Bt + t * BK;
        glds16(Ag + gA0, s + sW);                 // A line 0 (rows 0..127)
        glds16(Ag + gA1, s + 4096 + sW);          // A line 1 (rows 128..255)
        glds16(Bg + gA0, s + 8192 + sW);          // B line 0 (rows 0..127)
    };

    f32x4 acc[4][4] = {};
    bf16x8 af[4], bv[4];

    // prologue: stage tiles 0,1; land tile 0 (vmcnt(3) keeps tile 1 in flight)
    stage(0, 0);
    stage(1, 1);
    asm volatile("s_waitcnt vmcnt(3)" ::: "memory");
    __builtin_amdgcn_s_barrier();
    __builtin_amdgcn_sched_barrier(0);

#define FRAGS(BUF)                                                             \
    { const char* ca_ = (const char*)smem + (BUF) * 24576;                     \
      _Pragma("unroll") for (int m = 0; m < 4; ++m)                            \
          af[m] = *(const bf16x8*)(ca_ + afb + m * 1024);                      \
      _Pragma("unroll") for (int n = 0; n < 4; ++n)                            \
          bv[n] = *(const bf16x8*)(ca_ + 16384 + bfb + n * 1024); }

#define MFMAS()                                                                \
    asm volatile("s_waitcnt lgkmcnt(0)" ::: "memory");                         \
    __builtin_amdgcn_sched_barrier(0);                                         \
    __builtin_amdgcn_s_setprio(1);                                             \
    _Pragma("unroll") for (int m = 0; m < 4; ++m)                              \
      _Pragma("unroll") for (int n = 0; n < 4; ++n)                            \
        acc[m][n] = __builtin_amdgcn_mfma_f32_16x16x32_bf16(af[m], bv[n], acc[m][n], 0, 0, 0); \
    __builtin_amdgcn_s_setprio(0);                                             \
    __builtin_amdgcn_sched_barrier(0);

#define STEADY(T, BUF)                                                         \
  {                                                                            \
    FRAGS(BUF)                                                                 \
    stage(((BUF) + 2) % 3, (T) + 2);  /* WAR-safe: that buf read at T-1 */     \
    MFMAS()                                                                    \
    asm volatile("s_waitcnt vmcnt(3)" ::: "memory");  /* T+1 landed */         \
    __builtin_amdgcn_s_barrier();                                              \
    __builtin_amdgcn_sched_barrier(0);                                         \
  }

    #pragma unroll 1
    for (int tb = 0; tb < NT - 3; tb += 3) {
        STEADY(tb,     0)
        STEADY(tb + 1, 1)
        STEADY(tb + 2, 2)
    }
    STEADY(NT - 3, 0)
    // tail tile NT-2 (buf 1): no stage; drain (only tile NT-1's 3 lines out)
    {
        FRAGS(1)
        MFMAS()
        asm volatile("s_waitcnt vmcnt(0)" ::: "memory");
        __builtin_amdgcn_s_barrier();
        __builtin_amdgcn_sched_barrier(0);
    }
    // tail tile NT-1 (buf 2): no stage, no publish
    {
        FRAGS(2)
        MFMAS()
    }
#undef STEADY
#undef MFMAS
#undef FRAGS

    if constexpr (!COLMAX) {
        // C/D layout: col = fr, row = kq*4 + r  [verified m89/m91]
        u16* C = Cb + (size_t)batch * M * N + (size_t)(mt * BM + wr * 64) * N + nc * BN + wc * 64;
        #pragma unroll
        for (int m = 0; m < 4; ++m)
            #pragma unroll
            for (int n = 0; n < 4; ++n)
                #pragma unroll
                for (int r = 0; r < 4; ++r)
                    C[(size_t)(m * 16 + kq * 4 + r) * N + n * 16 + fr] = f2bf(acc[m][n][r]);
    } else {
        #pragma unroll
        for (int n = 0; n < 4; ++n) {
            float v = -3.4e38f;
            #pragma unroll
            for (int m = 0; m < 4; ++m)
                #pragma unroll
                for (int r = 0; r < 4; ++r)
                    v = fmaxf(v, acc[m][n][r]);
            v = fmaxf(v, __shfl_xor(v, 16));
            v = fmaxf(v, __shfl_xor(v, 32));
            if (lane < 16) cmax[wr][wc * 64 + n * 16 + fr] = v;
        }
        __syncthreads();
        if (tid < BN) {
            float v = fmaxf(fmaxf(cmax[0][tid], cmax[1][tid]),
                            fmaxf(cmax[2][tid], cmax[3][tid]));
            Pb[((size_t)batch * MT + mt) * N + nc * BN + tid] = v;
        }
    }
}

// alpha[b][t] = tanh(max over 8 row-tiles)
__global__ void k_alpha(const float* __restrict__ Pb, float* __restrict__ alpha) {
    int idx = blockIdx.x * 256 + threadIdx.x;   // NB*LTD
    int b = idx / LTD, tt = idx % LTD;
    float m = -3.4e38f;
    #pragma unroll
    for (int lt = 0; lt < 8; ++lt)
        m = fmaxf(m, Pb[((size_t)b * 8 + lt) * LTD + tt]);
    alpha[idx] = tanhf(m);
}

__global__ void k_ht_partial(const float* __restrict__ T, const float* __restrict__ alpha,
                             float* __restrict__ p2) {
    int bx = blockIdx.x;            // NB*3*8
    int tc = bx & 7;
    int r  = bx >> 3;
    int dc = r % 3, b = r / 3;
    int d = dc * 256 + threadIdx.x;
    const float* Tp = T + (size_t)b * LTD * DD + (size_t)tc * 256 * DD + d;
    const float* al = alpha + b * LTD + tc * 256;
    float s = 0.f;
    for (int t2 = 0; t2 < 256; ++t2)
        s += al[t2] * Tp[(size_t)t2 * DD];
    p2[((size_t)b * 8 + tc) * DD + d] = s;
}

__global__ void k_ht_reduce(const float* __restrict__ p2, float* __restrict__ out) {
    int idx = blockIdx.x * 256 + threadIdx.x;   // NB*DD
    int b = idx / DD, d = idx % DD;
    float s = 0.f;
    #pragma unroll
    for (int tc = 0; tc < 8; ++tc)
        s += p2[((size_t)b * 8 + tc) * DD + d];
    out[idx] = s;
}

extern "C" void kernel_launch(void* const* d_in, const int* in_sizes, int n_in,
                              void* d_out, int out_size, void* d_ws, size_t ws_size,
                              hipStream_t stream) {
    const float* H = (const float*)d_in[0];
    const float* T = (const float*)d_in[1];
    const float* W = (const float*)d_in[2];
    float* out = (float*)d_out;

    char* ws = (char*)d_ws;
    size_t off = 0;
    auto carve = [&](size_t bytes) -> void* {
        void* p = ws + off;
        off += (bytes + 255) & ~(size_t)255;
        return p;
    };
    u16*   R1    = (u16*)carve((size_t)NB * LHD * DD * 2);   // Hb, later reused as Tb
    u16*   z1    = (u16*)carve((size_t)NB * LHD * DD * 2);
    u16*   WT    = (u16*)carve((size_t)DD * DD * 2);
    float* Pb    = (float*)carve((size_t)NB * 8 * LTD * 4);
    float* alpha = (float*)carve((size_t)NB * LTD * 4);
    float* p2    = (float*)carve((size_t)NB * 8 * DD * 4);

    if (ws_size < off) return;

    const int n4 = NB * LHD * DD / 4;

    // 1. Hb = bf16(H)
    k_convert<<<4096, 256, 0, stream>>>(H, R1, n4);
    // 2. WT = bf16(W^T)
    k_transpose_w<<<(DD * DD) / 256, 256, 0, stream>>>(W, WT);
    // 3. z1 = Hb @ W   (grid 32*8*6 = 1536)
    k_gemm<false, LHD, DD, true>
        <<<NB * (LHD/256) * (DD/128), 512, 0, stream>>>(R1, WT, z1, nullptr);
    // 4. Tb = bf16(T) into R1 (Hb dead; stream-ordered)
    k_convert<<<4096, 256, 0, stream>>>(T, R1, n4);
    // 5. colmax(z1 @ T^T)  (grid 32*8*16 = 4096)
    k_gemm<true, LHD, LTD, false>
        <<<NB * (LHD/256) * (LTD/128), 512, 0, stream>>>(z1, R1, nullptr, Pb);
    // 6. alpha = tanh(max)
    k_alpha<<<NB * LTD / 256, 256, 0, stream>>>(Pb, alpha);
    // 7-8. HT = alpha @ T (f32)
    k_ht_partial<<<NB * 3 * 8, 256, 0, stream>>>(T, alpha, p2);
    k_ht_reduce<<<NB * DD / 256, 256, 0, stream>>>(p2, out);
}